// Round 11
// baseline (233.125 us; speedup 1.0000x reference)
//
#include <hip/hip_runtime.h>

// B=16 images, A=65536 anchors, G=32 gts. Inputs float32; output slot read as
// bf16 low-16-bits (dual-encode store gives absmax 0.0 -> keep it).
#define BB 16
#define AA 65536
#define GG 32
// Histogram: key = (float_bits>>14) - KOFF, bin 0 == 2^-10, 512 bins/octave.
// Count-only, value = bin midpoint (rel err <= 2^-10 << 2% budget).
#define NB 8192
#define KOFF 59904u          // __float_as_uint(2^-10) >> 14
#define AT 4                 // anchors per thread in k_matchforce
#define APB (256 * AT)       // 1024 anchors per block
#define MBLK (AA / APB)      // 64 match blocks per image
#define NSEG 16              // fused-stats segments per image
#define SEGA (AA / NSEG)     // 4096 anchors per fused block

// Static scratch: fully rewritten every call before any read (counters armed
// by k_matchforce block(0,0); kernel-boundary release/acquire makes them
// visible -- proven by the g_done pattern since R4). Re-poison safe. NO
// memset dispatch (R10 post-mortem: R8==R10 despite 8x fabric change =>
// dispatch count, not bytes, is the lever; 4 -> 2 dispatches this round).
__device__ unsigned char  g_mask[(size_t)BB * AA];
__device__ unsigned char  g_bidx[(size_t)BB * AA];
__device__ unsigned long long g_fpart[(size_t)BB * GG * MBLK];  // 256 KB
__device__ unsigned short g_nkey[(size_t)BB * NSEG * SEGA];     // 2 MB compact
__device__ int   g_ncnt[BB * NSEG];
__device__ float g_spart[BB * NSEG * 2];   // pos, loc partials
__device__ int   g_npart[BB * NSEG];
__device__ float g_loc[BB], g_pos[BB], g_neg[BB];
__device__ int   g_npos[BB], g_nneg[BB];
__device__ int   g_sdone[BB];              // per-image stats-arrival counter
__device__ int   g_done;                   // cross-image final-combine counter

__device__ __forceinline__ float midval(int bin) {
    return __uint_as_float((((unsigned int)bin + KOFF) << 14) | 8192u);
}

// ---------------------------------------------------------------------------
// Kernel 1: fused per-anchor match + per-gt force-match partials. (R6-proven)
// grid (MBLK=64, B), block 256, AT=4 anchors/thread (strided, coalesced).
// Divide-free scoring: r = inter/(areaA+areaG), monotone in IoU (iou=r/(1-r)),
// argmax-equivalent; iou>0.5 <=> r>1/3. rcp 1-ulp absorbed by bf16 budget
// (R2-R10 benches: absmax 0.0).
// Per gt: thread reduces its AT candidates in registers to
// key=(r_bits<<32)|(~offset) (tie-break = lowest offset, exact), 6-level
// __shfl_xor u64 butterfly, lane0 -> wkey[wave][g]; after barrier t<32 folds
// the 4 wave partials and writes g_fpart[b][g][blk] (plain store, no init
// needed -- every slot written every call).
__global__ void __launch_bounds__(256, 4)
k_matchforce(const float4* __restrict__ anchors,
             const float4* __restrict__ gts) {
    __shared__ float4 sg[GG];
    __shared__ unsigned long long wkey[4][GG];
    const int b = blockIdx.y;
    const int t = threadIdx.x;
    const int wave = t >> 6, lane = t & 63;
    if (blockIdx.x == 0 && b == 0) {          // arm handoff counters
        if (t < BB) g_sdone[t] = 0;
        else if (t == BB) g_done = 0;
    }
    if (t < GG) sg[t] = gts[(size_t)b * GG + t];
    __syncthreads();

    const size_t abase = (size_t)b * AA + (size_t)blockIdx.x * APB;

    float ax0[AT], ay0[AT], ax1[AT], ay1[AT], aar[AT], best[AT];
    int bg[AT];
#pragma unroll
    for (int j = 0; j < AT; ++j) {
        const float4 av = anchors[abase + j * 256 + t];
        ax0[j] = av.x; ay0[j] = av.y; ax1[j] = av.z; ay1[j] = av.w;
        aar[j] = (av.z - av.x) * (av.w - av.y);
        best[j] = -1.0f; bg[j] = 0;
    }

#pragma unroll 2
    for (int g = 0; g < GG; ++g) {
        const float4 gb = sg[g];
        const float ga = (gb.z - gb.x) * (gb.w - gb.y);
        float fbest = -1.0f;              // r >= 0 always -> j=0 wins init
        int fo = t;                       // block-local offset of j=0 anchor
#pragma unroll
        for (int j = 0; j < AT; ++j) {
            const float lx = fmaxf(ax0[j], gb.x), ly = fmaxf(ay0[j], gb.y);
            const float rx = fminf(ax1[j], gb.z), ry = fminf(ay1[j], gb.w);
            const float w = fmaxf(rx - lx, 0.0f), h = fmaxf(ry - ly, 0.0f);
            const float inter = w * h;
            const float s = aar[j] + ga;                    // areaA + areaG > 0
            const float r = inter * __builtin_amdgcn_rcpf(s);
            if (r > best[j]) { best[j] = r; bg[j] = g; }    // strict >: first max
            if (r > fbest)   { fbest = r; fo = j * 256 + t; }
        }
        // packed key: fbest >= 0 so float bits are unsigned-monotone; low word
        // = ~offset so larger key == smaller anchor offset on value ties.
        unsigned long long key =
            ((unsigned long long)__float_as_uint(fbest) << 32) |
            (unsigned long long)(0xFFFFFFFFu - (unsigned int)fo);
#pragma unroll
        for (int off = 1; off < 64; off <<= 1) {
            const unsigned long long o = __shfl_xor(key, off, 64);
            if (o > key) key = o;
        }
        if (lane == 0) wkey[wave][g] = key;
    }

#pragma unroll
    for (int j = 0; j < AT; ++j) {
        g_mask[abase + j * 256 + t] = (best[j] > (1.0f / 3.0f)) ? 1 : 0;
        g_bidx[abase + j * 256 + t] = (unsigned char)bg[j];
    }
    __syncthreads();
    if (t < GG) {
        unsigned long long k = wkey[0][t];
#pragma unroll
        for (int w = 1; w < 4; ++w) {
            const unsigned long long k1 = wkey[w][t];
            if (k1 > k) k = k1;
        }
        const unsigned int off = 0xFFFFFFFFu - (unsigned int)(k & 0xFFFFFFFFull);
        const unsigned int ga = (unsigned int)(blockIdx.x * APB) + off;
        g_fpart[((size_t)b * GG + t) * MBLK + blockIdx.x] =
            (k & 0xFFFFFFFF00000000ull) |
            (unsigned long long)(0xFFFFFFFFu - ga);
    }
}

// ---------------------------------------------------------------------------
// Kernel 2: FUSED stats + per-image select. grid (NSEG=16, B), block 1024,
// ~55 KB LDS (1 block/CU, 16 waves/CU).
// Stats phase (per segment of 4096 anchors): fold the 64 fpart partials per
// gt (t>>5 = gt, t&31 = chunk of 2, 5-level shfl width 32), mark in-segment
// forced winners in a 512 B bitmap; main pass = 4 anchors/thread; negatives
// compacted to LDS u16 keys, <=8 KB streamed out (R10-proven multiset).
// Handoff: __threadfence + atomicAdd(g_sdone[b]); the LAST-arriving block of
// each image becomes its select block (same fence+counter pattern as the
// final combine, passing since R4; no same-dispatch pre-write reads of the
// key fabric, so post-fence plain loads are safe). Select overlaps other
// images' stats; one kernel boundary disappears.
__global__ void __launch_bounds__(1024)
k_fused(const float4* __restrict__ bbox,
        const float* __restrict__ conf,
        const float4* __restrict__ gts,
        unsigned int* __restrict__ out) {
    __shared__ float4 sg[GG];
    __shared__ unsigned int bmap[SEGA / 32];  // 512 B forced-positive bitmap
    __shared__ unsigned short nk[SEGA];       // 8 KB compact negative keys
    __shared__ unsigned int ncnt;
    __shared__ float rf[1024], rf2[1024];     // 8 KB
    __shared__ unsigned int ru[1024];         // 4 KB
    __shared__ unsigned int hist[NB];         // 32 KB (select phase)
    __shared__ unsigned int s2[32];
    __shared__ int scw[NSEG];
    __shared__ int sh_np, sh_k, sh_bsel, sh_last;
    __shared__ float sh_pos, sh_loc;
    __shared__ unsigned int sh_take;

    const int b = blockIdx.y, seg = blockIdx.x, t = threadIdx.x;
    if (t < GG) sg[t] = gts[(size_t)b * GG + t];
    if (t < SEGA / 32) bmap[t] = 0u;
    if (t == 0) ncnt = 0u;
    __syncthreads();

    // fold force-match partials; mark winners landing in this segment
    {
        const int gg = t >> 5, p = t & 31;    // 1024 threads = 32 gts x 32
        const unsigned long long* fp =
            &g_fpart[((size_t)b * GG + gg) * MBLK + p * 2];
        unsigned long long k = fp[0];
        { const unsigned long long v = fp[1]; if (v > k) k = v; }
#pragma unroll
        for (int off = 1; off < 32; off <<= 1) {
            const unsigned long long o = __shfl_xor(k, off, 32);
            if (o > k) k = o;
        }
        if (p == 0) {
            const unsigned int a = 0xFFFFFFFFu - (unsigned int)(k & 0xFFFFFFFFull);
            const int la = (int)a - seg * SEGA;
            if (la >= 0 && la < SEGA) atomicOr(&bmap[la >> 5], 1u << (la & 31));
        }
    }
    __syncthreads();

    const size_t base = (size_t)b * AA + (size_t)seg * SEGA;   // anchor units
    const float4* c4 = (const float4*)(conf + base);
    const uchar4* m4 = (const uchar4*)(g_mask + base);
    const uchar4* x4 = (const uchar4*)(g_bidx + base);
    const float4* bb4 = bbox + base;

    float pos = 0.0f, loc = 0.0f;
    int np = 0;
    {
        const int idx = t;                     // 4 consecutive anchors/thread
        const float4 p4 = c4[idx];
        const uchar4 mm = m4[idx];
        const uchar4 xx = x4[idx];
        const unsigned int bw = (bmap[idx >> 3] >> ((idx & 7) * 4)) & 0xFu;
        const float pv[4] = {p4.x, p4.y, p4.z, p4.w};
        const unsigned char mv[4] = {mm.x, mm.y, mm.z, mm.w};
        const unsigned char xv[4] = {xx.x, xx.y, xx.z, xx.w};
        unsigned short lk[4];                  // this thread's negative keys
        int ln = 0;
#pragma unroll
        for (int c = 0; c < 4; ++c) {
            const float p = pv[c];
            if (mv[c] | ((bw >> c) & 1u)) {
                np += 1;
                pos += -logf(p);
                const float4 bv = bb4[4 * idx + c];
                const float4 gb = sg[xv[c]];
                const float d0 = (bv.x + bv.z) * 0.5f - (gb.x + gb.z) * 0.5f;
                const float d1 = (bv.y + bv.w) * 0.5f - (gb.y + gb.w) * 0.5f;
                const float d2 = (bv.z - bv.x) - (gb.z - gb.x);
                const float d3 = (bv.w - bv.y) - (gb.w - gb.y);
                float ds[4] = {d0, d1, d2, d3};
#pragma unroll
                for (int q = 0; q < 4; ++q) {
                    float ax = fabsf(ds[q]);
                    loc += (ax < 1.0f) ? 0.5f * ax * ax : ax - 0.5f;
                }
            } else {
                const float nb = -log1pf(-p);
                int key = (int)(__float_as_uint(nb) >> 14) - (int)KOFF;
                key = key < 0 ? 0 : (key > NB - 1 ? NB - 1 : key);
                lk[ln++] = (unsigned short)key;
            }
        }
        if (ln) {
            const unsigned int slot = atomicAdd(&ncnt, (unsigned int)ln);
            for (int i = 0; i < ln; ++i) nk[slot + i] = lk[i];
        }
    }
    // block reduce np/pos/loc; barriers also fence nk/ncnt
    ru[t] = (unsigned int)np; rf[t] = pos; rf2[t] = loc;
    __syncthreads();
    // pad to even with sentinel (ncnt odd => ncnt <= 4095, in bounds)
    if (t == 0 && (ncnt & 1u)) nk[ncnt] = 0xFFFFu;
    for (int w = 512; w > 0; w >>= 1) {
        if (t < w) { ru[t] += ru[t + w]; rf[t] += rf[t + w]; rf2[t] += rf2[t + w]; }
        __syncthreads();
    }
    if (t == 0) {
        g_npart[b * NSEG + seg] = (int)ru[0];
        g_spart[(b * NSEG + seg) * 2 + 0] = rf[0];
        g_spart[(b * NSEG + seg) * 2 + 1] = rf2[0];
        g_ncnt[b * NSEG + seg] = (int)ncnt;
    }
    // coalesced u32 writeout of the compact keys
    {
        const unsigned int cw = (ncnt + 1u) >> 1;
        const unsigned int* nk32 = (const unsigned int*)nk;
        unsigned int* outk =
            (unsigned int*)(g_nkey + ((size_t)b * NSEG + seg) * SEGA);
        for (unsigned int j = t; j < cw; j += 1024) outk[j] = nk32[j];
    }

    // ---- handoff: last-arriving block of image b runs the select phase ----
    __threadfence();                           // publish keys/partials
    if (t == 0) {
        const int old = atomicAdd(&g_sdone[b], 1);
        sh_last = (old == NSEG - 1);
    }
    __syncthreads();
    if (!sh_last) return;
    __threadfence();                           // acquire others' data

    // ===== select phase (one block per image, 1024 threads) =====
    for (int j = t; j < NB; j += 1024) hist[j] = 0u;
    if (t < NSEG) scw[t] = (g_ncnt[b * NSEG + t] + 1) >> 1;
    if (t < NSEG) {                            // 16-lane seg-partial fold
        int np2 = g_npart[b * NSEG + t];
        float pos2 = g_spart[(b * NSEG + t) * 2 + 0];
        float loc2 = g_spart[(b * NSEG + t) * 2 + 1];
#pragma unroll
        for (int off = 8; off > 0; off >>= 1) {
            np2  += __shfl_xor(np2,  off, 16);
            pos2 += __shfl_xor(pos2, off, 16);
            loc2 += __shfl_xor(loc2, off, 16);
        }
        if (t == 0) { sh_np = np2; sh_pos = pos2; sh_loc = loc2; }
    }
    __syncthreads();
    // flattened histogram of the compact keys (order-invariant -> bit-exact)
    {
        const unsigned int* kbase =
            (const unsigned int*)(g_nkey + (size_t)b * NSEG * SEGA);
        for (int w = t; w < NSEG * (SEGA / 2); w += 1024) {
            const int s = w >> 11;            // SEGA/2 = 2048 u32 words/segment
            const int j = w & 2047;
            if (j < scw[s]) {
                const unsigned int v = kbase[w];
                atomicAdd(&hist[v & 0xFFFFu], 1u);           // lo always valid
                const unsigned int k1 = v >> 16;
                if (k1 != 0xFFFFu) atomicAdd(&hist[k1], 1u); // hi unless pad
            }
        }
    }
    __syncthreads();
    const int np_tot = sh_np;

    // descending chunk counts: thread t covers bins NB-1-8t .. NB-8-8t
    unsigned int c = 0;
    const int hi = NB - 1 - t * 8;
#pragma unroll
    for (int j = 0; j < 8; ++j) c += hist[hi - j];
    ru[t] = c;
    __syncthreads();
    if (t < 32) {
        unsigned int x = 0;
#pragma unroll
        for (int j = 0; j < 32; ++j) x += ru[t * 32 + j];
        s2[t] = x;
    }
    __syncthreads();
    if (t == 0) {
        int k = 3 * np_tot;
        const int maxneg = AA - np_tot;
        if (k > maxneg) k = maxneg;
        sh_k = k;
        int bsel = NB;            // NB => nothing selected
        unsigned int take = 0;
        if (k > 0) {
            unsigned int cum = 0;
            int u = 0;
            while (u < 31 && cum + s2[u] < (unsigned int)k) { cum += s2[u]; ++u; }
            int cc = u * 32;
            while (cc < 1023 && cum + ru[cc] < (unsigned int)k) { cum += ru[cc]; ++cc; }
            const int h2 = NB - 1 - cc * 8;
            int j = 0;
            while (j < 7 && cum + hist[h2 - j] < (unsigned int)k) { cum += hist[h2 - j]; ++j; }
            bsel = h2 - j;
            take = (unsigned int)k - cum;
        }
        sh_bsel = bsel; sh_take = take;
    }
    __syncthreads();
    const int bsel = sh_bsel;
    float negp = 0.0f;
    for (int j = t; j < NB; j += 1024)
        if (j > bsel) { unsigned int cnt = hist[j]; if (cnt) negp += (float)cnt * midval(j); }
    rf[t] = negp;
    __syncthreads();
    for (int w = 512; w > 0; w >>= 1) {
        if (t < w) rf[t] += rf[t + w];
        __syncthreads();
    }
    if (t == 0) {
        float neg = 0.0f;
        if (sh_k > 0) neg = rf[0] + (float)sh_take * midval(bsel < NB ? bsel : 0);
        g_loc[b] = sh_loc; g_pos[b] = sh_pos; g_neg[b] = neg;
        g_npos[b] = np_tot; g_nneg[b] = sh_k;

        __threadfence();                        // publish before counting in
        const int old = atomicAdd(&g_done, 1);
        if (old == BB - 1) {                    // last image: final combine
            __threadfence();
            float loc = 0.0f, conf2 = 0.0f;
            int tot = 0;
            for (int bb = 0; bb < BB; ++bb) {
                const float lv = __hip_atomic_load(&g_loc[bb],  __ATOMIC_RELAXED, __HIP_MEMORY_SCOPE_AGENT);
                const float pv = __hip_atomic_load(&g_pos[bb],  __ATOMIC_RELAXED, __HIP_MEMORY_SCOPE_AGENT);
                const float nv = __hip_atomic_load(&g_neg[bb],  __ATOMIC_RELAXED, __HIP_MEMORY_SCOPE_AGENT);
                const int   np2 = __hip_atomic_load(&g_npos[bb], __ATOMIC_RELAXED, __HIP_MEMORY_SCOPE_AGENT);
                const int   nn = __hip_atomic_load(&g_nneg[bb], __ATOMIC_RELAXED, __HIP_MEMORY_SCOPE_AGENT);
                loc += lv;
                conf2 += pv / (float)(np2 > 1 ? np2 : 1) +
                         nv / (float)(nn > 1 ? nn : 1);
                tot += np2;
            }
            const float total = loc / (float)(tot > 1 ? tot : 1) + conf2 / (float)BB;
            const unsigned int u = __float_as_uint(total);
            const unsigned int r = 0x7FFFu + ((u >> 16) & 1u);
            const unsigned int bf = (u + r) >> 16;      // bf16(total), RNE
            out[0] = (bf << 16) | bf;
        }
    }
}

extern "C" void kernel_launch(void* const* d_in, const int* in_sizes, int n_in,
                              void* d_out, int out_size, void* d_ws, size_t ws_size,
                              hipStream_t stream) {
    const float4* bbox    = (const float4*)d_in[0];
    const float*  conf    = (const float*)d_in[1];
    const float4* anchors = (const float4*)d_in[2];
    const float4* gts     = (const float4*)d_in[3];

    k_matchforce<<<dim3(MBLK, BB), 256, 0, stream>>>(anchors, gts);
    k_fused<<<dim3(NSEG, BB), 1024, 0, stream>>>(bbox, conf, gts,
                                                 (unsigned int*)d_out);
}

// Round 12
// 126.991 us; speedup vs baseline: 1.8358x; 1.8358x over previous
//
#include <hip/hip_runtime.h>

// B=16 images, A=65536 anchors, G=32 gts. Inputs float32; output slot read as
// bf16 low-16-bits (dual-encode store gives absmax 0.0 -> keep it).
// R12 = R6 structure (best measured: 132.1us) + 1024-thread k_stats.
// R11 post-mortem: fusion kernel was scratch-bound (runtime-indexed lk[] ->
// VGPR 32, VALUBusy 5%) + 256 device-scope fences. Reverted wholesale.
#define BB 16
#define AA 65536
#define GG 32
// Histogram: key = (float_bits>>14) - KOFF, bin 0 == 2^-10, 512 bins/octave.
// Count-only, value = bin midpoint (rel err <= 2^-10 << 2% budget).
#define NB 8192
#define KOFF 59904u          // __float_as_uint(2^-10) >> 14
#define AT 4                 // anchors per thread in k_matchforce
#define APB (256 * AT)       // 1024 anchors per block
#define MBLK (AA / APB)      // 64 match blocks per image
#define NSEG 16              // stats segments per image
#define SEGA (AA / NSEG)     // 4096 anchors per stats block

// All scratch in device globals; every buffer fully rewritten each call
// before being read (g_done armed by k_matchforce). Re-poison safe.
__device__ unsigned char      g_mask[(size_t)BB * AA];
__device__ unsigned char      g_bidx[(size_t)BB * AA];
__device__ unsigned long long g_fpart[(size_t)BB * GG * MBLK];  // 256 KB
__device__ unsigned int       g_hpart[(size_t)BB * NSEG * (NB/2)]; // 4 MB packed
__device__ float g_spart[BB * NSEG * 2];   // pos, loc partials
__device__ int   g_npart[BB * NSEG];
__device__ float g_loc[BB], g_pos[BB], g_neg[BB];
__device__ int   g_npos[BB], g_nneg[BB];
__device__ int   g_done;                   // armed to 0 by k_matchforce

__device__ __forceinline__ float midval(int bin) {
    return __uint_as_float((((unsigned int)bin + KOFF) << 14) | 8192u);
}

// ---------------------------------------------------------------------------
// Kernel 1: fused per-anchor match + per-gt force-match partials. (R6-proven)
// grid (MBLK=64, B), block 256, AT=4 anchors/thread (strided, coalesced).
// Divide-free scoring: r = inter/(areaA+areaG), monotone in IoU (iou=r/(1-r)),
// argmax-equivalent; iou>0.5 <=> r>1/3. rcp 1-ulp absorbed by bf16 budget
// (R2-R11 benches: absmax 0.0).
// Per gt: thread reduces its AT candidates in registers to
// key=(r_bits<<32)|(~offset) (tie-break = lowest offset, exact), 6-level
// __shfl_xor u64 butterfly, lane0 -> wkey[wave][g]; after barrier t<32 folds
// the 4 wave partials and writes g_fpart[b][g][blk] (plain store, no init).
__global__ void __launch_bounds__(256, 4)
k_matchforce(const float4* __restrict__ anchors,
             const float4* __restrict__ gts) {
    __shared__ float4 sg[GG];
    __shared__ unsigned long long wkey[4][GG];
    const int b = blockIdx.y;
    const int t = threadIdx.x;
    const int wave = t >> 6, lane = t & 63;
    if (blockIdx.x == 0 && b == 0 && t == 0) g_done = 0;   // arm final combine
    if (t < GG) sg[t] = gts[(size_t)b * GG + t];
    __syncthreads();

    const size_t abase = (size_t)b * AA + (size_t)blockIdx.x * APB;

    float ax0[AT], ay0[AT], ax1[AT], ay1[AT], aar[AT], best[AT];
    int bg[AT];
#pragma unroll
    for (int j = 0; j < AT; ++j) {
        const float4 av = anchors[abase + j * 256 + t];
        ax0[j] = av.x; ay0[j] = av.y; ax1[j] = av.z; ay1[j] = av.w;
        aar[j] = (av.z - av.x) * (av.w - av.y);
        best[j] = -1.0f; bg[j] = 0;
    }

#pragma unroll 2
    for (int g = 0; g < GG; ++g) {
        const float4 gb = sg[g];
        const float ga = (gb.z - gb.x) * (gb.w - gb.y);
        float fbest = -1.0f;              // r >= 0 always -> j=0 wins init
        int fo = t;                       // block-local offset of j=0 anchor
#pragma unroll
        for (int j = 0; j < AT; ++j) {
            const float lx = fmaxf(ax0[j], gb.x), ly = fmaxf(ay0[j], gb.y);
            const float rx = fminf(ax1[j], gb.z), ry = fminf(ay1[j], gb.w);
            const float w = fmaxf(rx - lx, 0.0f), h = fmaxf(ry - ly, 0.0f);
            const float inter = w * h;
            const float s = aar[j] + ga;                    // areaA + areaG > 0
            const float r = inter * __builtin_amdgcn_rcpf(s);
            if (r > best[j]) { best[j] = r; bg[j] = g; }    // strict >: first max
            if (r > fbest)   { fbest = r; fo = j * 256 + t; }
        }
        // packed key: fbest >= 0 so float bits are unsigned-monotone; low word
        // = ~offset so larger key == smaller anchor offset on value ties.
        unsigned long long key =
            ((unsigned long long)__float_as_uint(fbest) << 32) |
            (unsigned long long)(0xFFFFFFFFu - (unsigned int)fo);
#pragma unroll
        for (int off = 1; off < 64; off <<= 1) {
            const unsigned long long o = __shfl_xor(key, off, 64);
            if (o > key) key = o;
        }
        if (lane == 0) wkey[wave][g] = key;
    }

#pragma unroll
    for (int j = 0; j < AT; ++j) {
        g_mask[abase + j * 256 + t] = (best[j] > (1.0f / 3.0f)) ? 1 : 0;
        g_bidx[abase + j * 256 + t] = (unsigned char)bg[j];
    }
    __syncthreads();
    if (t < GG) {
        unsigned long long k = wkey[0][t];
#pragma unroll
        for (int w = 1; w < 4; ++w) {
            const unsigned long long k1 = wkey[w][t];
            if (k1 > k) k = k1;
        }
        const unsigned int off = 0xFFFFFFFFu - (unsigned int)(k & 0xFFFFFFFFull);
        const unsigned int ga = (unsigned int)(blockIdx.x * APB) + off;
        g_fpart[((size_t)b * GG + t) * MBLK + blockIdx.x] =
            (k & 0xFFFFFFFF00000000ull) |
            (unsigned long long)(0xFFFFFFFFu - ga);
    }
}

// ---------------------------------------------------------------------------
// Kernel 2: segmented per-image stats. grid (NSEG=16, B), block 1024.
// R12 delta vs R6 (the ONLY change this round): 256 -> 1024 threads. Same
// grid, same 16 KB LDS-hist, same 16-partial fabric. R6 ran 1 wave/SIMD
// (zero latency hiding -- the R4 lesson); now 16 waves/CU. Each thread
// handles 4 consecutive anchors (one iteration). No runtime-indexed local
// arrays (R11 lesson), no global atomics (R7), no fences here.
// fpart fold: 1024 threads = 32 gts x 32 chunks of 2, 5-level shfl width 32;
// chunk-0 lanes mark in-segment winners in a 512 B bitmap.
__global__ void __launch_bounds__(1024)
k_stats(const float4* __restrict__ bbox,
        const float* __restrict__ conf,
        const float4* __restrict__ gts) {
    __shared__ float4 sg[GG];
    __shared__ unsigned int hp[NB / 2];       // 16 KB packed hist (u16 counts)
    __shared__ unsigned int bmap[SEGA / 32];  // 512 B forced-positive bitmap
    __shared__ float rf[1024], rf2[1024];
    __shared__ unsigned int ru[1024];
    const int b = blockIdx.y, seg = blockIdx.x, t = threadIdx.x;
    if (t < GG) sg[t] = gts[(size_t)b * GG + t];
    for (int j = t; j < NB / 2; j += 1024) hp[j] = 0u;
    if (t < SEGA / 32) bmap[t] = 0u;
    __syncthreads();

    // fold force-match winners; mark ones landing in this segment
    {
        const int gg = t >> 5, p = t & 31;    // 1024 threads = 32 gts x 32
        const unsigned long long* fp =
            &g_fpart[((size_t)b * GG + gg) * MBLK + p * 2];
        unsigned long long k = fp[0];
        { const unsigned long long v = fp[1]; if (v > k) k = v; }
#pragma unroll
        for (int off = 1; off < 32; off <<= 1) {
            const unsigned long long o = __shfl_xor(k, off, 32);
            if (o > k) k = o;
        }
        if (p == 0) {
            const unsigned int a = 0xFFFFFFFFu - (unsigned int)(k & 0xFFFFFFFFull);
            const int la = (int)a - seg * SEGA;
            if (la >= 0 && la < SEGA) atomicOr(&bmap[la >> 5], 1u << (la & 31));
        }
    }
    __syncthreads();

    const size_t base = (size_t)b * AA + (size_t)seg * SEGA;   // anchor units
    const float4* c4 = (const float4*)(conf + base);
    const uchar4* m4 = (const uchar4*)(g_mask + base);
    const uchar4* x4 = (const uchar4*)(g_bidx + base);
    const float4* bb4 = bbox + base;

    float pos = 0.0f, loc = 0.0f;
    int np = 0;
    {
        const int idx = t;                     // 4 consecutive anchors/thread
        const float4 p4 = c4[idx];
        const uchar4 mm = m4[idx];
        const uchar4 xx = x4[idx];
        const unsigned int bw = (bmap[idx >> 3] >> ((idx & 7) * 4)) & 0xFu;
        const float pv[4] = {p4.x, p4.y, p4.z, p4.w};
        const unsigned char mv[4] = {mm.x, mm.y, mm.z, mm.w};
        const unsigned char xv[4] = {xx.x, xx.y, xx.z, xx.w};
#pragma unroll
        for (int c = 0; c < 4; ++c) {
            const float p = pv[c];
            if (mv[c] | ((bw >> c) & 1u)) {
                np += 1;
                pos += -logf(p);
                const float4 bv = bb4[4 * idx + c];
                const float4 gb = sg[xv[c]];
                const float d0 = (bv.x + bv.z) * 0.5f - (gb.x + gb.z) * 0.5f;
                const float d1 = (bv.y + bv.w) * 0.5f - (gb.y + gb.w) * 0.5f;
                const float d2 = (bv.z - bv.x) - (gb.z - gb.x);
                const float d3 = (bv.w - bv.y) - (gb.w - gb.y);
                float ds[4] = {d0, d1, d2, d3};
#pragma unroll
                for (int q = 0; q < 4; ++q) {
                    float ax = fabsf(ds[q]);
                    loc += (ax < 1.0f) ? 0.5f * ax * ax : ax - 0.5f;
                }
            } else {
                const float nb = -log1pf(-p);
                int key = (int)(__float_as_uint(nb) >> 14) - (int)KOFF;
                key = key < 0 ? 0 : (key > NB - 1 ? NB - 1 : key);
                atomicAdd(&hp[key >> 1], 1u << ((key & 1) << 4));
            }
        }
    }
    // block reduce np/pos/loc (barriers also fence the LDS hist atomics)
    ru[t] = (unsigned int)np; rf[t] = pos; rf2[t] = loc;
    __syncthreads();
    for (int w = 512; w > 0; w >>= 1) {
        if (t < w) { ru[t] += ru[t + w]; rf[t] += rf[t + w]; rf2[t] += rf2[t + w]; }
        __syncthreads();
    }
    if (t == 0) {
        g_npart[b * NSEG + seg] = (int)ru[0];
        g_spart[(b * NSEG + seg) * 2 + 0] = rf[0];
        g_spart[(b * NSEG + seg) * 2 + 1] = rf2[0];
    }
    unsigned int* outp = g_hpart + ((size_t)b * NSEG + seg) * (NB / 2);
    for (int j = t; j < NB / 2; j += 1024) outp[j] = hp[j];
}

// ---------------------------------------------------------------------------
// Kernel 3: per-image fold + hard-negative top-k + (last block) final combine.
// grid B, block 1024. (R6-proven, unchanged.)
__global__ void __launch_bounds__(1024) k_select(unsigned int* __restrict__ out) {
    __shared__ unsigned int hist[NB];         // 32 KB
    __shared__ unsigned int ru[1024];
    __shared__ unsigned int s2[32];
    __shared__ float sh_pos, sh_loc;
    __shared__ int sh_np, sh_k, sh_bsel;
    __shared__ unsigned int sh_take;
    __shared__ float rf[1024];

    const int b = blockIdx.x, t = threadIdx.x;
    // fold 16 packed partial hists -> u32 LDS hist
    for (int w = t; w < NB / 2; w += 1024) {
        unsigned int lo = 0, hi = 0;
#pragma unroll
        for (int s = 0; s < NSEG; ++s) {
            const unsigned int v = g_hpart[((size_t)b * NSEG + s) * (NB / 2) + w];
            lo += v & 0xFFFFu; hi += v >> 16;
        }
        hist[2 * w] = lo; hist[2 * w + 1] = hi;
    }
    if (t < NSEG) {                            // 16-lane seg-partial fold
        int np = g_npart[b * NSEG + t];
        float pos = g_spart[(b * NSEG + t) * 2 + 0];
        float loc = g_spart[(b * NSEG + t) * 2 + 1];
#pragma unroll
        for (int off = 8; off > 0; off >>= 1) {
            np  += __shfl_xor(np,  off, 16);
            pos += __shfl_xor(pos, off, 16);
            loc += __shfl_xor(loc, off, 16);
        }
        if (t == 0) { sh_np = np; sh_pos = pos; sh_loc = loc; }
    }
    __syncthreads();
    const int np_tot = sh_np;

    // descending chunk counts: thread t covers bins NB-1-8t .. NB-8-8t
    unsigned int c = 0;
    const int hi = NB - 1 - t * 8;
#pragma unroll
    for (int j = 0; j < 8; ++j) c += hist[hi - j];
    ru[t] = c;
    __syncthreads();
    if (t < 32) {
        unsigned int x = 0;
#pragma unroll
        for (int j = 0; j < 32; ++j) x += ru[t * 32 + j];
        s2[t] = x;
    }
    __syncthreads();
    if (t == 0) {
        int k = 3 * np_tot;
        const int maxneg = AA - np_tot;
        if (k > maxneg) k = maxneg;
        sh_k = k;
        int bsel = NB;            // NB => nothing selected
        unsigned int take = 0;
        if (k > 0) {
            unsigned int cum = 0;
            int u = 0;
            while (u < 31 && cum + s2[u] < (unsigned int)k) { cum += s2[u]; ++u; }
            int cc = u * 32;
            while (cc < 1023 && cum + ru[cc] < (unsigned int)k) { cum += ru[cc]; ++cc; }
            const int h2 = NB - 1 - cc * 8;
            int j = 0;
            while (j < 7 && cum + hist[h2 - j] < (unsigned int)k) { cum += hist[h2 - j]; ++j; }
            bsel = h2 - j;
            take = (unsigned int)k - cum;
        }
        sh_bsel = bsel; sh_take = take;
    }
    __syncthreads();
    const int bsel = sh_bsel;
    float negp = 0.0f;
    for (int j = t; j < NB; j += 1024)
        if (j > bsel) { unsigned int cnt = hist[j]; if (cnt) negp += (float)cnt * midval(j); }
    rf[t] = negp;
    __syncthreads();
    for (int w = 512; w > 0; w >>= 1) {
        if (t < w) rf[t] += rf[t + w];
        __syncthreads();
    }
    if (t == 0) {
        float neg = 0.0f;
        if (sh_k > 0) neg = rf[0] + (float)sh_take * midval(bsel < NB ? bsel : 0);
        g_loc[b] = sh_loc; g_pos[b] = sh_pos; g_neg[b] = neg;
        g_npos[b] = np_tot; g_nneg[b] = sh_k;

        __threadfence();                        // publish before counting in
        const int old = atomicAdd(&g_done, 1);
        if (old == BB - 1) {                    // last image: final combine
            __threadfence();
            float loc = 0.0f, conf = 0.0f;
            int tot = 0;
            for (int bb = 0; bb < BB; ++bb) {
                const float lv = __hip_atomic_load(&g_loc[bb],  __ATOMIC_RELAXED, __HIP_MEMORY_SCOPE_AGENT);
                const float pv = __hip_atomic_load(&g_pos[bb],  __ATOMIC_RELAXED, __HIP_MEMORY_SCOPE_AGENT);
                const float nv = __hip_atomic_load(&g_neg[bb],  __ATOMIC_RELAXED, __HIP_MEMORY_SCOPE_AGENT);
                const int   np = __hip_atomic_load(&g_npos[bb], __ATOMIC_RELAXED, __HIP_MEMORY_SCOPE_AGENT);
                const int   nn = __hip_atomic_load(&g_nneg[bb], __ATOMIC_RELAXED, __HIP_MEMORY_SCOPE_AGENT);
                loc += lv;
                conf += pv / (float)(np > 1 ? np : 1) +
                        nv / (float)(nn > 1 ? nn : 1);
                tot += np;
            }
            const float total = loc / (float)(tot > 1 ? tot : 1) + conf / (float)BB;
            const unsigned int u = __float_as_uint(total);
            const unsigned int r = 0x7FFFu + ((u >> 16) & 1u);
            const unsigned int bf = (u + r) >> 16;      // bf16(total), RNE
            out[0] = (bf << 16) | bf;
        }
    }
}

extern "C" void kernel_launch(void* const* d_in, const int* in_sizes, int n_in,
                              void* d_out, int out_size, void* d_ws, size_t ws_size,
                              hipStream_t stream) {
    const float4* bbox    = (const float4*)d_in[0];
    const float*  conf    = (const float*)d_in[1];
    const float4* anchors = (const float4*)d_in[2];
    const float4* gts     = (const float4*)d_in[3];

    k_matchforce<<<dim3(MBLK, BB), 256, 0, stream>>>(anchors, gts);
    k_stats<<<dim3(NSEG, BB), 1024, 0, stream>>>(bbox, conf, gts);
    k_select<<<BB, 1024, 0, stream>>>((unsigned int*)d_out);
}